// Round 2
// baseline (183.888 us; speedup 1.0000x reference)
//
#include <hip/hip_runtime.h>

constexpr int EMB = 256;
constexpr float FEPS = 1e-6f;
constexpr int RELDIMS = 2 * EMB;                 // 512 dims per relation (2 heads)
constexpr size_t PRE_ARR = 1024u * RELDIMS;      // elements per SoA array (max n_rel=1024)
constexpr size_t PRE_BYTES = 4 * PRE_ARR * sizeof(float);  // 8 MB total

__device__ __forceinline__ float ftanh(float x) {
    x = fminf(15.f, fmaxf(-15.f, x));
    float t = __expf(2.f * x);
    return (t - 1.f) * __builtin_amdgcn_rcpf(t + 1.f);
}

// ---------------- precompute: per-(relation, dim) constants ----------------
// ct  = tanh(center)
// thr = w/2            (w = tanh(|width|/gmean * (1+elu(box_size))))
// wp1 = w + 1
// kap = 0.5*w*(wp1 - 1/wp1)
__global__ __launch_bounds__(256) void boxe_pre(
    const float* __restrict__ rel, int n_rel,
    float* __restrict__ ct, float* __restrict__ thr,
    float* __restrict__ wp1a, float* __restrict__ kap)
{
    const int r    = (blockIdx.x * blockDim.x + threadIdx.x) >> 6;
    const int lane = threadIdx.x & 63;
    if (r >= n_rel) return;
    const float* __restrict__ rrow = rel + (long)r * (4 * EMB + 2);
    const int d0 = lane * 4;

    float c0[4], c1[4], w0[4], w1[4];
    *(float4*)c0 = *(const float4*)(rrow + d0);
    *(float4*)c1 = *(const float4*)(rrow + EMB + d0);
    *(float4*)w0 = *(const float4*)(rrow + 2 * EMB + d0);
    *(float4*)w1 = *(const float4*)(rrow + 3 * EMB + d0);
    const float bs0 = rrow[4 * EMB + 0];
    const float bs1 = rrow[4 * EMB + 1];

    float wa0[4], wa1[4], ls0 = 0.f, ls1 = 0.f;
#pragma unroll
    for (int j = 0; j < 4; ++j) {
        wa0[j] = fabsf(w0[j]);
        wa1[j] = fabsf(w1[j]);
        ls0 += __logf(fmaxf(wa0[j], FEPS));
        ls1 += __logf(fmaxf(wa1[j], FEPS));
    }
#pragma unroll
    for (int off = 32; off >= 1; off >>= 1) {
        ls0 += __shfl_xor(ls0, off, 64);
        ls1 += __shfl_xor(ls1, off, 64);
    }
    const float g0 = __expf(ls0 * (1.f / (float)EMB));
    const float g1 = __expf(ls1 * (1.f / (float)EMB));
    const float e0 = (bs0 > 0.f) ? bs0 : (__expf(bs0) - 1.f);
    const float e1 = (bs1 > 0.f) ? bs1 : (__expf(bs1) - 1.f);
    const float s0 = (1.f + e0) / fmaxf(g0, FEPS);
    const float s1 = (1.f + e1) / fmaxf(g1, FEPS);

    float octa[4], othr[4], owp1[4], okap[4];
    const int base0 = r * RELDIMS + d0;          // head 0
    const int base1 = base0 + EMB;               // head 1
#pragma unroll
    for (int j = 0; j < 4; ++j) {
        float w   = ftanh(wa0[j] * s0);
        float wp1 = w + 1.f;
        octa[j] = ftanh(c0[j]);
        othr[j] = 0.5f * w;
        owp1[j] = wp1;
        okap[j] = 0.5f * w * (wp1 - 1.f / wp1);
    }
    *(float4*)(ct   + base0) = *(float4*)octa;
    *(float4*)(thr  + base0) = *(float4*)othr;
    *(float4*)(wp1a + base0) = *(float4*)owp1;
    *(float4*)(kap  + base0) = *(float4*)okap;
#pragma unroll
    for (int j = 0; j < 4; ++j) {
        float w   = ftanh(wa1[j] * s1);
        float wp1 = w + 1.f;
        octa[j] = ftanh(c1[j]);
        othr[j] = 0.5f * w;
        owp1[j] = wp1;
        okap[j] = 0.5f * w * (wp1 - 1.f / wp1);
    }
    *(float4*)(ct   + base1) = *(float4*)octa;
    *(float4*)(thr  + base1) = *(float4*)othr;
    *(float4*)(wp1a + base1) = *(float4*)owp1;
    *(float4*)(kap  + base1) = *(float4*)okap;
}

// ---------------- main: one wave per batch row ----------------
__global__ __launch_bounds__(256) void boxe_main(
    const float* __restrict__ head, const int* __restrict__ rid,
    const float* __restrict__ tail,
    const float* __restrict__ ct, const float* __restrict__ thr,
    const float* __restrict__ wp1a, const float* __restrict__ kap,
    float* __restrict__ out, int batch)
{
    const int b    = (int)(((size_t)blockIdx.x * blockDim.x + threadIdx.x) >> 6);
    const int lane = threadIdx.x & 63;
    if (b >= batch) return;

    const int r = rid[b];
    const int d0 = lane * 4;
    const float* __restrict__ hrow = head + (long)b * RELDIMS;
    const float* __restrict__ trow = tail + (long)b * RELDIMS;
    const int base0 = r * RELDIMS + d0;
    const int base1 = base0 + EMB;

    float hp[4], hb[4], tp[4], tb[4];
    *(float4*)hp = *(const float4*)(hrow + d0);
    *(float4*)hb = *(const float4*)(hrow + EMB + d0);
    *(float4*)tp = *(const float4*)(trow + d0);
    *(float4*)tb = *(const float4*)(trow + EMB + d0);

    float acc0 = 0.f, acc1 = 0.f;
    {
        float pct[4], pth[4], pw1[4], pkp[4];
        *(float4*)pct = *(const float4*)(ct   + base0);
        *(float4*)pth = *(const float4*)(thr  + base0);
        *(float4*)pw1 = *(const float4*)(wp1a + base0);
        *(float4*)pkp = *(const float4*)(kap  + base0);
#pragma unroll
        for (int j = 0; j < 4; ++j) {
            float bt  = ftanh(hp[j] + tb[j]);
            float cd  = fabsf(bt - pct[j]);
            float inv = __builtin_amdgcn_rcpf(pw1[j]);
            float d   = (cd <= pth[j]) ? (cd * inv) : fmaf(cd, pw1[j], -pkp[j]);
            acc0 = fmaf(d, d, acc0);
        }
    }
    {
        float pct[4], pth[4], pw1[4], pkp[4];
        *(float4*)pct = *(const float4*)(ct   + base1);
        *(float4*)pth = *(const float4*)(thr  + base1);
        *(float4*)pw1 = *(const float4*)(wp1a + base1);
        *(float4*)pkp = *(const float4*)(kap  + base1);
#pragma unroll
        for (int j = 0; j < 4; ++j) {
            float bt  = ftanh(tp[j] + hb[j]);
            float cd  = fabsf(bt - pct[j]);
            float inv = __builtin_amdgcn_rcpf(pw1[j]);
            float d   = (cd <= pth[j]) ? (cd * inv) : fmaf(cd, pw1[j], -pkp[j]);
            acc1 = fmaf(d, d, acc1);
        }
    }
#pragma unroll
    for (int off = 32; off >= 1; off >>= 1) {
        acc0 += __shfl_xor(acc0, off, 64);
        acc1 += __shfl_xor(acc1, off, 64);
    }
    if (lane == 0) out[b] = -(sqrtf(acc0) + sqrtf(acc1));
}

// ---------------- fallback (R1 fused kernel) if ws too small ----------------
__device__ __forceinline__ float dist2_term(float wabs, float scale, float c, float bm) {
    float w   = ftanh(wabs * scale);
    float ctv = ftanh(c);
    float bt  = ftanh(bm);
    float cd  = fabsf(bt - ctv);
    float wp1 = w + 1.f;
    float inv = __builtin_amdgcn_rcpf(wp1);
    float kappa = 0.5f * w * (wp1 - inv);
    float dist = (cd <= 0.5f * w) ? (cd * inv) : fmaf(cd, wp1, -kappa);
    return dist * dist;
}

__global__ __launch_bounds__(256) void boxe_fused(
    const float* __restrict__ head, const int* __restrict__ rid,
    const float* __restrict__ tail, const float* __restrict__ rel,
    float* __restrict__ out, int batch)
{
    const int b    = (int)(((size_t)blockIdx.x * blockDim.x + threadIdx.x) >> 6);
    const int lane = threadIdx.x & 63;
    if (b >= batch) return;
    const long r = rid[b];
    const float* __restrict__ rrow = rel  + r * (long)(4 * EMB + 2);
    const float* __restrict__ hrow = head + (long)b * RELDIMS;
    const float* __restrict__ trow = tail + (long)b * RELDIMS;
    const int d0 = lane * 4;
    float hp[4], hb[4], tp[4], tb[4], c0[4], c1[4], w0[4], w1[4];
    *(float4*)hp = *(const float4*)(hrow + d0);
    *(float4*)hb = *(const float4*)(hrow + EMB + d0);
    *(float4*)tp = *(const float4*)(trow + d0);
    *(float4*)tb = *(const float4*)(trow + EMB + d0);
    *(float4*)c0 = *(const float4*)(rrow + d0);
    *(float4*)c1 = *(const float4*)(rrow + EMB + d0);
    *(float4*)w0 = *(const float4*)(rrow + 2 * EMB + d0);
    *(float4*)w1 = *(const float4*)(rrow + 3 * EMB + d0);
    const float bs0 = rrow[4 * EMB + 0];
    const float bs1 = rrow[4 * EMB + 1];
    float wa0[4], wa1[4], ls0 = 0.f, ls1 = 0.f;
#pragma unroll
    for (int j = 0; j < 4; ++j) {
        wa0[j] = fabsf(w0[j]); wa1[j] = fabsf(w1[j]);
        ls0 += __logf(fmaxf(wa0[j], FEPS)); ls1 += __logf(fmaxf(wa1[j], FEPS));
    }
#pragma unroll
    for (int off = 32; off >= 1; off >>= 1) {
        ls0 += __shfl_xor(ls0, off, 64); ls1 += __shfl_xor(ls1, off, 64);
    }
    const float g0 = __expf(ls0 * (1.f / 256.f)), g1 = __expf(ls1 * (1.f / 256.f));
    const float e0 = (bs0 > 0.f) ? bs0 : (__expf(bs0) - 1.f);
    const float e1 = (bs1 > 0.f) ? bs1 : (__expf(bs1) - 1.f);
    const float s0 = (1.f + e0) / fmaxf(g0, FEPS);
    const float s1 = (1.f + e1) / fmaxf(g1, FEPS);
    float acc0 = 0.f, acc1 = 0.f;
#pragma unroll
    for (int j = 0; j < 4; ++j) {
        acc0 += dist2_term(wa0[j], s0, c0[j], hp[j] + tb[j]);
        acc1 += dist2_term(wa1[j], s1, c1[j], tp[j] + hb[j]);
    }
#pragma unroll
    for (int off = 32; off >= 1; off >>= 1) {
        acc0 += __shfl_xor(acc0, off, 64); acc1 += __shfl_xor(acc1, off, 64);
    }
    if (lane == 0) out[b] = -(sqrtf(acc0) + sqrtf(acc1));
}

extern "C" void kernel_launch(void* const* d_in, const int* in_sizes, int n_in,
                              void* d_out, int out_size, void* d_ws, size_t ws_size,
                              hipStream_t stream) {
    const float* head = (const float*)d_in[0];
    const int*   rid  = (const int*)d_in[1];
    const float* tail = (const float*)d_in[2];
    const float* rel  = (const float*)d_in[3];
    float* out = (float*)d_out;

    const int batch = out_size;                       // 131072
    const int n_rel = in_sizes[3] / (4 * EMB + 2);    // 1024
    const int blocks = (batch + 3) / 4;               // 4 waves/block

    if (ws_size >= PRE_BYTES && n_rel <= 1024) {
        float* ct   = (float*)d_ws;
        float* thr  = ct   + PRE_ARR;
        float* wp1a = thr  + PRE_ARR;
        float* kap  = wp1a + PRE_ARR;
        boxe_pre<<<(n_rel + 3) / 4, 256, 0, stream>>>(rel, n_rel, ct, thr, wp1a, kap);
        boxe_main<<<blocks, 256, 0, stream>>>(head, rid, tail, ct, thr, wp1a, kap, out, batch);
    } else {
        boxe_fused<<<blocks, 256, 0, stream>>>(head, rid, tail, rel, out, batch);
    }
}

// Round 3
// 126.543 us; speedup vs baseline: 1.4532x; 1.4532x over previous
//
#include <hip/hip_runtime.h>

constexpr int EMB = 256;
constexpr float FEPS = 1e-6f;
constexpr int RELDIMS = 2 * EMB;                       // 512 dims per relation
// interleaved {ct, wp1} per (rel, dim): 1024 rel * 512 * 2 floats = 4 MB
constexpr size_t PRE_FLOATS = 1024u * RELDIMS * 2;
constexpr size_t PRE_BYTES  = PRE_FLOATS * sizeof(float);

__device__ __forceinline__ float ftanh(float x) {
    x = fminf(15.f, fmaxf(-15.f, x));
    float t = __expf(2.f * x);
    return (t - 1.f) * __builtin_amdgcn_rcpf(t + 1.f);
}

// ---------------- precompute: interleaved {tanh(center), w+1} ----------------
__global__ __launch_bounds__(256) void boxe_pre(
    const float* __restrict__ rel, int n_rel, float* __restrict__ pre)
{
    const int r    = (blockIdx.x * blockDim.x + threadIdx.x) >> 6;
    const int lane = threadIdx.x & 63;
    if (r >= n_rel) return;
    const float* __restrict__ rrow = rel + (long)r * (4 * EMB + 2);
    const int d0 = lane * 4;

    float c0[4], c1[4], w0[4], w1[4];
    *(float4*)c0 = *(const float4*)(rrow + d0);
    *(float4*)c1 = *(const float4*)(rrow + EMB + d0);
    *(float4*)w0 = *(const float4*)(rrow + 2 * EMB + d0);
    *(float4*)w1 = *(const float4*)(rrow + 3 * EMB + d0);
    const float bs0 = rrow[4 * EMB + 0];
    const float bs1 = rrow[4 * EMB + 1];

    float wa0[4], wa1[4], ls0 = 0.f, ls1 = 0.f;
#pragma unroll
    for (int j = 0; j < 4; ++j) {
        wa0[j] = fabsf(w0[j]);
        wa1[j] = fabsf(w1[j]);
        ls0 += __logf(fmaxf(wa0[j], FEPS));
        ls1 += __logf(fmaxf(wa1[j], FEPS));
    }
#pragma unroll
    for (int off = 32; off >= 1; off >>= 1) {
        ls0 += __shfl_xor(ls0, off, 64);
        ls1 += __shfl_xor(ls1, off, 64);
    }
    const float g0 = __expf(ls0 * (1.f / (float)EMB));
    const float g1 = __expf(ls1 * (1.f / (float)EMB));
    const float e0 = (bs0 > 0.f) ? bs0 : (__expf(bs0) - 1.f);
    const float e1 = (bs1 > 0.f) ? bs1 : (__expf(bs1) - 1.f);
    const float s0 = (1.f + e0) / fmaxf(g0, FEPS);
    const float s1 = (1.f + e1) / fmaxf(g1, FEPS);

    float* __restrict__ prow = pre + (long)r * (RELDIMS * 2);
    float pa[4], pb[4];
#pragma unroll
    for (int j = 0; j < 4; ++j) {            // head 0
        float ct  = ftanh(c0[j]);
        float wp1 = ftanh(wa0[j] * s0) + 1.f;
        if (j < 2) { pa[j * 2] = ct; pa[j * 2 + 1] = wp1; }
        else       { pb[(j - 2) * 2] = ct; pb[(j - 2) * 2 + 1] = wp1; }
    }
    *(float4*)(prow + d0 * 2)     = *(float4*)pa;
    *(float4*)(prow + d0 * 2 + 4) = *(float4*)pb;
#pragma unroll
    for (int j = 0; j < 4; ++j) {            // head 1
        float ct  = ftanh(c1[j]);
        float wp1 = ftanh(wa1[j] * s1) + 1.f;
        if (j < 2) { pa[j * 2] = ct; pa[j * 2 + 1] = wp1; }
        else       { pb[(j - 2) * 2] = ct; pb[(j - 2) * 2 + 1] = wp1; }
    }
    *(float4*)(prow + (EMB + d0) * 2)     = *(float4*)pa;
    *(float4*)(prow + (EMB + d0) * 2 + 4) = *(float4*)pb;
}

// ---------------- main: one wave per batch row ----------------
__device__ __forceinline__ float d2term(float ct, float wp1, float bm, float& /*dummy*/) {
    return 0.f;
}

__global__ __launch_bounds__(256) void boxe_main(
    const float* __restrict__ head, const int* __restrict__ rid,
    const float* __restrict__ tail, const float* __restrict__ pre,
    float* __restrict__ out, int batch)
{
    const int b    = (int)(((size_t)blockIdx.x * blockDim.x + threadIdx.x) >> 6);
    const int lane = threadIdx.x & 63;
    if (b >= batch) return;

    const int r  = rid[b];
    const int d0 = lane * 4;
    const float* __restrict__ hrow = head + (long)b * RELDIMS;
    const float* __restrict__ trow = tail + (long)b * RELDIMS;
    const float* __restrict__ prow = pre + (long)r * (RELDIMS * 2);

    float hp[4], hb[4], tp[4], tb[4];
    *(float4*)hp = *(const float4*)(hrow + d0);
    *(float4*)hb = *(const float4*)(hrow + EMB + d0);
    *(float4*)tp = *(const float4*)(trow + d0);
    *(float4*)tb = *(const float4*)(trow + EMB + d0);

    float p0[8], p1[8];   // {ct,wp1} x4 dims, head0 / head1
    *(float4*)(p0)     = *(const float4*)(prow + d0 * 2);
    *(float4*)(p0 + 4) = *(const float4*)(prow + d0 * 2 + 4);
    *(float4*)(p1)     = *(const float4*)(prow + (EMB + d0) * 2);
    *(float4*)(p1 + 4) = *(const float4*)(prow + (EMB + d0) * 2 + 4);

    float acc0 = 0.f, acc1 = 0.f;
#pragma unroll
    for (int j = 0; j < 4; ++j) {
        // head 0: bumped = head_pos + tail_bump
        {
            float ct  = p0[j * 2], wp1 = p0[j * 2 + 1];
            float w   = wp1 - 1.f;
            float inv = __builtin_amdgcn_rcpf(wp1);
            float bt  = ftanh(hp[j] + tb[j]);
            float cd  = fabsf(bt - ct);
            float kap = 0.5f * w * (wp1 - inv);
            float d   = (cd <= 0.5f * w) ? (cd * inv) : fmaf(cd, wp1, -kap);
            acc0 = fmaf(d, d, acc0);
        }
        // head 1: bumped = tail_pos + head_bump
        {
            float ct  = p1[j * 2], wp1 = p1[j * 2 + 1];
            float w   = wp1 - 1.f;
            float inv = __builtin_amdgcn_rcpf(wp1);
            float bt  = ftanh(tp[j] + hb[j]);
            float cd  = fabsf(bt - ct);
            float kap = 0.5f * w * (wp1 - inv);
            float d   = (cd <= 0.5f * w) ? (cd * inv) : fmaf(cd, wp1, -kap);
            acc1 = fmaf(d, d, acc1);
        }
    }
#pragma unroll
    for (int off = 32; off >= 1; off >>= 1) {
        acc0 += __shfl_xor(acc0, off, 64);
        acc1 += __shfl_xor(acc1, off, 64);
    }
    if (lane == 0) out[b] = -(sqrtf(acc0) + sqrtf(acc1));
}

// ---------------- fallback (R1 fused kernel) if ws too small ----------------
__device__ __forceinline__ float dist2_term(float wabs, float scale, float c, float bm) {
    float w   = ftanh(wabs * scale);
    float ctv = ftanh(c);
    float bt  = ftanh(bm);
    float cd  = fabsf(bt - ctv);
    float wp1 = w + 1.f;
    float inv = __builtin_amdgcn_rcpf(wp1);
    float kappa = 0.5f * w * (wp1 - inv);
    float dist = (cd <= 0.5f * w) ? (cd * inv) : fmaf(cd, wp1, -kappa);
    return dist * dist;
}

__global__ __launch_bounds__(256) void boxe_fused(
    const float* __restrict__ head, const int* __restrict__ rid,
    const float* __restrict__ tail, const float* __restrict__ rel,
    float* __restrict__ out, int batch)
{
    const int b    = (int)(((size_t)blockIdx.x * blockDim.x + threadIdx.x) >> 6);
    const int lane = threadIdx.x & 63;
    if (b >= batch) return;
    const long r = rid[b];
    const float* __restrict__ rrow = rel  + r * (long)(4 * EMB + 2);
    const float* __restrict__ hrow = head + (long)b * RELDIMS;
    const float* __restrict__ trow = tail + (long)b * RELDIMS;
    const int d0 = lane * 4;
    float hp[4], hb[4], tp[4], tb[4], c0[4], c1[4], w0[4], w1[4];
    *(float4*)hp = *(const float4*)(hrow + d0);
    *(float4*)hb = *(const float4*)(hrow + EMB + d0);
    *(float4*)tp = *(const float4*)(trow + d0);
    *(float4*)tb = *(const float4*)(trow + EMB + d0);
    *(float4*)c0 = *(const float4*)(rrow + d0);
    *(float4*)c1 = *(const float4*)(rrow + EMB + d0);
    *(float4*)w0 = *(const float4*)(rrow + 2 * EMB + d0);
    *(float4*)w1 = *(const float4*)(rrow + 3 * EMB + d0);
    const float bs0 = rrow[4 * EMB + 0];
    const float bs1 = rrow[4 * EMB + 1];
    float wa0[4], wa1[4], ls0 = 0.f, ls1 = 0.f;
#pragma unroll
    for (int j = 0; j < 4; ++j) {
        wa0[j] = fabsf(w0[j]); wa1[j] = fabsf(w1[j]);
        ls0 += __logf(fmaxf(wa0[j], FEPS)); ls1 += __logf(fmaxf(wa1[j], FEPS));
    }
#pragma unroll
    for (int off = 32; off >= 1; off >>= 1) {
        ls0 += __shfl_xor(ls0, off, 64); ls1 += __shfl_xor(ls1, off, 64);
    }
    const float g0 = __expf(ls0 * (1.f / 256.f)), g1 = __expf(ls1 * (1.f / 256.f));
    const float e0 = (bs0 > 0.f) ? bs0 : (__expf(bs0) - 1.f);
    const float e1 = (bs1 > 0.f) ? bs1 : (__expf(bs1) - 1.f);
    const float s0 = (1.f + e0) / fmaxf(g0, FEPS);
    const float s1 = (1.f + e1) / fmaxf(g1, FEPS);
    float acc0 = 0.f, acc1 = 0.f;
#pragma unroll
    for (int j = 0; j < 4; ++j) {
        acc0 += dist2_term(wa0[j], s0, c0[j], hp[j] + tb[j]);
        acc1 += dist2_term(wa1[j], s1, c1[j], tp[j] + hb[j]);
    }
#pragma unroll
    for (int off = 32; off >= 1; off >>= 1) {
        acc0 += __shfl_xor(acc0, off, 64); acc1 += __shfl_xor(acc1, off, 64);
    }
    if (lane == 0) out[b] = -(sqrtf(acc0) + sqrtf(acc1));
}

extern "C" void kernel_launch(void* const* d_in, const int* in_sizes, int n_in,
                              void* d_out, int out_size, void* d_ws, size_t ws_size,
                              hipStream_t stream) {
    const float* head = (const float*)d_in[0];
    const int*   rid  = (const int*)d_in[1];
    const float* tail = (const float*)d_in[2];
    const float* rel  = (const float*)d_in[3];
    float* out = (float*)d_out;

    const int batch = out_size;                       // 131072
    const int n_rel = in_sizes[3] / (4 * EMB + 2);    // 1024
    const int blocks = (batch + 3) / 4;               // 4 waves/block

    const size_t need = (size_t)n_rel * RELDIMS * 2 * sizeof(float);
    if (ws_size >= need && n_rel <= 1024) {
        float* pre = (float*)d_ws;
        boxe_pre<<<(n_rel + 3) / 4, 256, 0, stream>>>(rel, n_rel, pre);
        boxe_main<<<blocks, 256, 0, stream>>>(head, rid, tail, pre, out, batch);
    } else {
        boxe_fused<<<blocks, 256, 0, stream>>>(head, rid, tail, rel, out, batch);
    }
}

// Round 4
// 114.215 us; speedup vs baseline: 1.6100x; 1.1079x over previous
//
#include <hip/hip_runtime.h>
#include <hip/hip_fp16.h>

constexpr int EMB = 256;
constexpr int RELDIMS = 512;
constexpr float FEPS = 1e-6f;
constexpr int ROWS = 8;     // rows per wave (2-deep prefetch pipeline)
constexpr int WPB  = 4;     // waves per block

__device__ __forceinline__ float ftanh(float x) {
    x = fminf(15.f, fmaxf(-15.f, x));
    float t = __expf(2.f * x);
    return (t - 1.f) * __builtin_amdgcn_rcpf(t + 1.f);
}

// ---------- precompute: packed fp16 {ct, wp1} per (rel, dim); word = h*EMB+d ----------
__global__ __launch_bounds__(256) void boxe_pre(
    const float* __restrict__ rel, int n_rel, unsigned int* __restrict__ pre)
{
    const int r    = (blockIdx.x * blockDim.x + threadIdx.x) >> 6;
    const int lane = threadIdx.x & 63;
    if (r >= n_rel) return;
    const float* __restrict__ rrow = rel + (long)r * (4 * EMB + 2);
    const int d0 = lane * 4;

    float c0[4], c1[4], w0[4], w1[4];
    *(float4*)c0 = *(const float4*)(rrow + d0);
    *(float4*)c1 = *(const float4*)(rrow + EMB + d0);
    *(float4*)w0 = *(const float4*)(rrow + 2 * EMB + d0);
    *(float4*)w1 = *(const float4*)(rrow + 3 * EMB + d0);
    const float bs0 = rrow[4 * EMB + 0];
    const float bs1 = rrow[4 * EMB + 1];

    float wa0[4], wa1[4], ls0 = 0.f, ls1 = 0.f;
#pragma unroll
    for (int j = 0; j < 4; ++j) {
        wa0[j] = fabsf(w0[j]); wa1[j] = fabsf(w1[j]);
        ls0 += __logf(fmaxf(wa0[j], FEPS));
        ls1 += __logf(fmaxf(wa1[j], FEPS));
    }
#pragma unroll
    for (int off = 32; off >= 1; off >>= 1) {
        ls0 += __shfl_xor(ls0, off, 64);
        ls1 += __shfl_xor(ls1, off, 64);
    }
    const float g0 = __expf(ls0 * (1.f / (float)EMB));
    const float g1 = __expf(ls1 * (1.f / (float)EMB));
    const float e0 = (bs0 > 0.f) ? bs0 : (__expf(bs0) - 1.f);
    const float e1 = (bs1 > 0.f) ? bs1 : (__expf(bs1) - 1.f);
    const float s0 = (1.f + e0) / fmaxf(g0, FEPS);
    const float s1 = (1.f + e1) / fmaxf(g1, FEPS);

    unsigned int* __restrict__ prow = pre + (long)r * RELDIMS;
    unsigned int pk[4];
#pragma unroll
    for (int j = 0; j < 4; ++j) {
        __half2 h2 = __floats2half2_rn(ftanh(c0[j]), ftanh(wa0[j] * s0) + 1.f);
        pk[j] = *(unsigned int*)&h2;
    }
    *(uint4*)(prow + d0) = make_uint4(pk[0], pk[1], pk[2], pk[3]);
#pragma unroll
    for (int j = 0; j < 4; ++j) {
        __half2 h2 = __floats2half2_rn(ftanh(c1[j]), ftanh(wa1[j] * s1) + 1.f);
        pk[j] = *(unsigned int*)&h2;
    }
    *(uint4*)(prow + EMB + d0) = make_uint4(pk[0], pk[1], pk[2], pk[3]);
}

// ---------- main: lane owns 8 dims of one head; 8 rows/wave, 2-deep prefetch ----------
__global__ __launch_bounds__(256, 4) void boxe_main(
    const float* __restrict__ head, const int* __restrict__ rid,
    const float* __restrict__ tail, const unsigned int* __restrict__ pre,
    float* __restrict__ out)
{
    const int wave = blockIdx.x * WPB + (threadIdx.x >> 6);
    const int lane = threadIdx.x & 63;
    const int b0   = wave * ROWS;

    // lane l: half = l>>5, dims (l&31)*8 .. +8
    const int fidx = lane * 8;          // float idx in head row (pos for low lanes, bump for high)
    const int tidx = (lane ^ 32) * 8;   // float idx in tail row (bump for low lanes, pos for high)

    int ridv[ROWS];
    {
        int4 ra = *(const int4*)(rid + b0);
        int4 rb = *(const int4*)(rid + b0 + 4);
        ridv[0] = ra.x; ridv[1] = ra.y; ridv[2] = ra.z; ridv[3] = ra.w;
        ridv[4] = rb.x; ridv[5] = rb.y; ridv[6] = rb.z; ridv[7] = rb.w;
    }

    float4 hbuf[2][2], tbuf[2][2];
    uint4  pbuf[2][2];

    {   // prologue: row 0 -> buffer 0
        const float* hrow = head + (size_t)b0 * RELDIMS;
        const float* trow = tail + (size_t)b0 * RELDIMS;
        const unsigned int* prow = pre + (size_t)ridv[0] * RELDIMS;
        hbuf[0][0] = *(const float4*)(hrow + fidx);
        hbuf[0][1] = *(const float4*)(hrow + fidx + 4);
        tbuf[0][0] = *(const float4*)(trow + tidx);
        tbuf[0][1] = *(const float4*)(trow + tidx + 4);
        pbuf[0][0] = *(const uint4*)(prow + fidx);
        pbuf[0][1] = *(const uint4*)(prow + fidx + 4);
    }

#pragma unroll
    for (int i = 0; i < ROWS; ++i) {
        const int cur = i & 1, nxt = cur ^ 1;
        if (i + 1 < ROWS) {   // issue next row's loads before current compute
            const int bn = b0 + i + 1;
            const float* hrow = head + (size_t)bn * RELDIMS;
            const float* trow = tail + (size_t)bn * RELDIMS;
            const unsigned int* prow = pre + (size_t)ridv[i + 1] * RELDIMS;
            hbuf[nxt][0] = *(const float4*)(hrow + fidx);
            hbuf[nxt][1] = *(const float4*)(hrow + fidx + 4);
            tbuf[nxt][0] = *(const float4*)(trow + tidx);
            tbuf[nxt][1] = *(const float4*)(trow + tidx + 4);
            pbuf[nxt][0] = *(const uint4*)(prow + fidx);
            pbuf[nxt][1] = *(const uint4*)(prow + fidx + 4);
        }

        float h[8], t[8];
        unsigned int pw[8];
        *(float4*)(h)     = hbuf[cur][0]; *(float4*)(h + 4) = hbuf[cur][1];
        *(float4*)(t)     = tbuf[cur][0]; *(float4*)(t + 4) = tbuf[cur][1];
        *(uint4*)(pw)     = pbuf[cur][0]; *(uint4*)(pw + 4) = pbuf[cur][1];

        float acc = 0.f;
#pragma unroll
        for (int j = 0; j < 8; ++j) {
            float2 cw = __half22float2(*(__half2*)&pw[j]);
            float ct = cw.x, wp1 = cw.y;
            float bt  = ftanh(h[j] + t[j]);          // bump = pos + other's bump
            float cd  = fabsf(bt - ct);
            float w   = wp1 - 1.f;
            float inv = __builtin_amdgcn_rcpf(wp1);
            float kap = 0.5f * w * (wp1 - inv);
            float d   = (cd <= 0.5f * w) ? (cd * inv) : fmaf(cd, wp1, -kap);
            acc = fmaf(d, d, acc);
        }
        // butterfly within each 32-lane half (both heads reduce simultaneously)
#pragma unroll
        for (int off = 16; off >= 1; off >>= 1)
            acc += __shfl_xor(acc, off, 64);
        float other = __shfl_xor(acc, 32, 64);
        if (lane == 0) out[b0 + i] = -(sqrtf(acc) + sqrtf(other));
    }
}

// ---------- fallback: R1 fused kernel ----------
__device__ __forceinline__ float dist2_term(float wabs, float scale, float c, float bm) {
    float w   = ftanh(wabs * scale);
    float ctv = ftanh(c);
    float bt  = ftanh(bm);
    float cd  = fabsf(bt - ctv);
    float wp1 = w + 1.f;
    float inv = __builtin_amdgcn_rcpf(wp1);
    float kappa = 0.5f * w * (wp1 - inv);
    float dist = (cd <= 0.5f * w) ? (cd * inv) : fmaf(cd, wp1, -kappa);
    return dist * dist;
}

__global__ __launch_bounds__(256) void boxe_fused(
    const float* __restrict__ head, const int* __restrict__ rid,
    const float* __restrict__ tail, const float* __restrict__ rel,
    float* __restrict__ out, int batch)
{
    const int b    = (int)(((size_t)blockIdx.x * blockDim.x + threadIdx.x) >> 6);
    const int lane = threadIdx.x & 63;
    if (b >= batch) return;
    const long r = rid[b];
    const float* __restrict__ rrow = rel  + r * (long)(4 * EMB + 2);
    const float* __restrict__ hrow = head + (long)b * RELDIMS;
    const float* __restrict__ trow = tail + (long)b * RELDIMS;
    const int d0 = lane * 4;
    float hp[4], hb[4], tp[4], tb[4], c0[4], c1[4], w0[4], w1[4];
    *(float4*)hp = *(const float4*)(hrow + d0);
    *(float4*)hb = *(const float4*)(hrow + EMB + d0);
    *(float4*)tp = *(const float4*)(trow + d0);
    *(float4*)tb = *(const float4*)(trow + EMB + d0);
    *(float4*)c0 = *(const float4*)(rrow + d0);
    *(float4*)c1 = *(const float4*)(rrow + EMB + d0);
    *(float4*)w0 = *(const float4*)(rrow + 2 * EMB + d0);
    *(float4*)w1 = *(const float4*)(rrow + 3 * EMB + d0);
    const float bs0 = rrow[4 * EMB + 0];
    const float bs1 = rrow[4 * EMB + 1];
    float wa0[4], wa1[4], ls0 = 0.f, ls1 = 0.f;
#pragma unroll
    for (int j = 0; j < 4; ++j) {
        wa0[j] = fabsf(w0[j]); wa1[j] = fabsf(w1[j]);
        ls0 += __logf(fmaxf(wa0[j], FEPS)); ls1 += __logf(fmaxf(wa1[j], FEPS));
    }
#pragma unroll
    for (int off = 32; off >= 1; off >>= 1) {
        ls0 += __shfl_xor(ls0, off, 64); ls1 += __shfl_xor(ls1, off, 64);
    }
    const float g0 = __expf(ls0 * (1.f / 256.f)), g1 = __expf(ls1 * (1.f / 256.f));
    const float e0 = (bs0 > 0.f) ? bs0 : (__expf(bs0) - 1.f);
    const float e1 = (bs1 > 0.f) ? bs1 : (__expf(bs1) - 1.f);
    const float s0 = (1.f + e0) / fmaxf(g0, FEPS);
    const float s1 = (1.f + e1) / fmaxf(g1, FEPS);
    float acc0 = 0.f, acc1 = 0.f;
#pragma unroll
    for (int j = 0; j < 4; ++j) {
        acc0 += dist2_term(wa0[j], s0, c0[j], hp[j] + tb[j]);
        acc1 += dist2_term(wa1[j], s1, c1[j], tp[j] + hb[j]);
    }
#pragma unroll
    for (int off = 32; off >= 1; off >>= 1) {
        acc0 += __shfl_xor(acc0, off, 64); acc1 += __shfl_xor(acc1, off, 64);
    }
    if (lane == 0) out[b] = -(sqrtf(acc0) + sqrtf(acc1));
}

extern "C" void kernel_launch(void* const* d_in, const int* in_sizes, int n_in,
                              void* d_out, int out_size, void* d_ws, size_t ws_size,
                              hipStream_t stream) {
    const float* head = (const float*)d_in[0];
    const int*   rid  = (const int*)d_in[1];
    const float* tail = (const float*)d_in[2];
    const float* rel  = (const float*)d_in[3];
    float* out = (float*)d_out;

    const int batch = out_size;                       // 131072
    const int n_rel = in_sizes[3] / (4 * EMB + 2);    // 1024
    const size_t need = (size_t)n_rel * RELDIMS * sizeof(unsigned int);  // 2 MB

    if (ws_size >= need && batch % (WPB * ROWS) == 0) {
        unsigned int* pre = (unsigned int*)d_ws;
        boxe_pre<<<(n_rel + 3) / 4, 256, 0, stream>>>(rel, n_rel, pre);
        const int blocks = batch / (WPB * ROWS);      // 4096
        boxe_main<<<blocks, 256, 0, stream>>>(head, rid, tail, pre, out);
    } else {
        const int blocks = (batch + 3) / 4;
        boxe_fused<<<blocks, 256, 0, stream>>>(head, rid, tail, rel, out, batch);
    }
}